// Round 8
// baseline (159.017 us; speedup 1.0000x reference)
//
#include <hip/hip_runtime.h>
#include <hip/hip_bf16.h>

// USM sharpen, fused: 2 kernels instead of 4. Each kernel does a FULL 2D
// separable 51-tap Gaussian on a 64x64 output tile with the vertical-pass
// intermediate (V) kept in LDS:
//   K1: img f32 --[vblur->V->hblur]--> res bf16 = img - blur2D(img)
//   K2: mask(res) --[vblur->V->hblur]--> soft_mask; out f32 = img + sm*(sharp-img)
// Both 1D convs are band-matrix MFMAs (verified in round 7):
//   out[i] = sum_r W[i][r] * in[tilebase + r],  W0[i][r] = g[r-i] (y-dir),
//   W1[i][r] = g[r-1-i] (x-dir; -1 compensates the alignment shift below).
// A/B/C fragment indexing identical to the round-7-verified kernel.
// Zero-hazard discipline: every LDS address reachable by an MFMA B-read is
// written finite (stage rows >=114 clamp-filled, V cols >=128 zero-filled,
// W zero outside [0,51)) so padded taps are exact-0 x finite.
// Stage x uses a -26 shift so 2-col/lane loads are 8B aligned; x-edge blocks
// (bx 0,7) use a scalar reflect path.

typedef __attribute__((ext_vector_type(8))) short bf16x8;
typedef __attribute__((ext_vector_type(4))) float f32x4;

constexpr int IMG = 512, NIMG = 48, K = 51;
constexpr int TILE = 64;     // output tile 64x64
constexpr int SCOLS = 128;   // staged x-cols (x = x0-26+c, c in [0,128))
constexpr int SROW = 168;    // stage y-space per col; mult-8, 84 words != 0 mod 32
constexpr int SDATA = 114;   // valid data rows (y halo 25+64+25)
constexpr int NCH = 18;      // stage chunks of 8 rows (covers s in [0,144))
constexpr int VROW = 152;    // V x-space; mult-8, 76 words = 12 mod 32 (bank spread)
constexpr int WAVES = 8;

__device__ __forceinline__ float bf2f(unsigned short u) {
    return __builtin_bit_cast(float, (unsigned)u << 16);
}
__device__ __forceinline__ unsigned short f2bf(float f) {
    unsigned u = __builtin_bit_cast(unsigned, f);
    u += 0x7FFF + ((u >> 16) & 1);  // RNE, finite inputs only
    return (unsigned short)(u >> 16);
}
__device__ __forceinline__ int refl(int i) {
    i = i < 0 ? -i : i;
    return i >= IMG ? 2 * IMG - 2 - i : i;
}
// stage index: column-major, y XOR-swizzled in bits 3-4 (8-row chunks stay
// contiguous/aligned; spreads columns across banks for b128 on both sides)
__device__ __forceinline__ int sidx(int c, int s) {
    return c * SROW + (s ^ ((c & 3) << 3));
}

// SRCB: src elem 0=f32, 1=bf16.  LOADM 1: mask(|v|*255>10) at stage time.
// STOREM 1: dst bf16 = img - blur2D.  STOREM 2: sm=blur2D; dst f32 = final.
template <int SRCB, int LOADM, int STOREM>
__global__ __launch_bounds__(512, 4) void fused_kern(const void* __restrict__ srcv,
                                                     const float* __restrict__ img,
                                                     const unsigned short* __restrict__ res,
                                                     void* __restrict__ dstv,
                                                     const float* __restrict__ k1d) {
    __shared__ unsigned short st[SCOLS * SROW];  // 43008 B staged input
    __shared__ unsigned short V[TILE * VROW];    // 19456 B vblur intermediate
    const int tid = threadIdx.x, lane = tid & 63;
    const int wv = __builtin_amdgcn_readfirstlane(tid >> 6);
    const int m = lane & 15, g = lane >> 4;
    const int x0 = blockIdx.x * TILE, y0 = blockIdx.y * TILE;
    const size_t base = (size_t)blockIdx.z * (IMG * IMG);

    // ---- W band fragments in registers (both directions) ----
    bf16x8 a0[3], a1[3];
#pragma unroll
    for (int rs = 0; rs < 3; ++rs) {
#pragma unroll
        for (int j = 0; j < 8; ++j) {
            const int i0 = rs * 32 + 8 * g + j - m;      // W0[i=m][r] = g[r-m]
            a0[rs][j] = ((unsigned)i0 < (unsigned)K) ? (short)f2bf(k1d[i0]) : (short)0;
            const int i1 = i0 - 1;                       // W1[i][r] = g[r-1-i]
            a1[rs][j] = ((unsigned)i1 < (unsigned)K) ? (short)f2bf(k1d[i1]) : (short)0;
        }
    }

    // ---- V zero tail: cols [128,152) finite (read-reachable, W-zero region) ----
    for (int i = tid; i < TILE * 12; i += 512) {
        const int r = i / 12, c2 = i - r * 12;
        *(unsigned*)&V[r * VROW + SCOLS + 2 * c2] = 0u;
    }

    // ---- stage: 2 cols/lane, 8 rows/chunk, b128 LDS writes ----
    const bool xedge = (blockIdx.x == 0) || (blockIdx.x == IMG / TILE - 1);
    for (int ch = wv; ch < NCH; ch += WAVES) {
        const int s0 = ch * 8;
        unsigned p0[4] = {0, 0, 0, 0}, p1[4] = {0, 0, 0, 0};
#pragma unroll
        for (int h = 0; h < 8; ++h) {
            const int sy = min(s0 + h, SDATA - 1);       // rows >=114: finite filler
            const size_t rowb = base + (size_t)refl(y0 - 25 + sy) * IMG;
            unsigned short u0, u1;
            if (SRCB == 0) {
                float v0, v1;
                if (!xedge) {
                    const float2 v = *(const float2*)&((const float*)srcv)[rowb + x0 - 26 + 2 * lane];
                    v0 = v.x; v1 = v.y;
                } else {
                    v0 = ((const float*)srcv)[rowb + refl(x0 - 26 + 2 * lane)];
                    v1 = ((const float*)srcv)[rowb + refl(x0 - 25 + 2 * lane)];
                }
                u0 = f2bf(v0); u1 = f2bf(v1);
            } else {
                if (!xedge) {
                    const unsigned v = *(const unsigned*)&((const unsigned short*)srcv)[rowb + x0 - 26 + 2 * lane];
                    u0 = (unsigned short)v; u1 = (unsigned short)(v >> 16);
                } else {
                    u0 = ((const unsigned short*)srcv)[rowb + refl(x0 - 26 + 2 * lane)];
                    u1 = ((const unsigned short*)srcv)[rowb + refl(x0 - 25 + 2 * lane)];
                }
                if (LOADM == 1) {
                    u0 = (fabsf(bf2f(u0)) * 255.0f > 10.0f) ? 0x3F80 : 0;
                    u1 = (fabsf(bf2f(u1)) * 255.0f > 10.0f) ? 0x3F80 : 0;
                }
            }
            p0[h >> 1] |= (unsigned)u0 << ((h & 1) * 16);
            p1[h >> 1] |= (unsigned)u1 << ((h & 1) * 16);
        }
        *(uint4*)&st[sidx(2 * lane, s0)]     = make_uint4(p0[0], p0[1], p0[2], p0[3]);
        *(uint4*)&st[sidx(2 * lane + 1, s0)] = make_uint4(p1[0], p1[1], p1[2], p1[3]);
    }
    __syncthreads();

    // ---- step 1: vblur -> V (32 tiles: 8 x-tiles x 4 y-tiles) ----
#pragma unroll
    for (int k4 = 0; k4 < 4; ++k4) {
        const int t = wv + 8 * k4;
        const int xs = t & 7, ys = t >> 3;
        f32x4 acc = {0.f, 0.f, 0.f, 0.f};
#pragma unroll
        for (int rs = 0; rs < 3; ++rs) {
            const bf16x8 b = *(const bf16x8*)&st[sidx(16 * xs + m, 16 * ys + rs * 32 + 8 * g)];
            acc = __builtin_amdgcn_mfma_f32_16x16x32_bf16(a0[rs], b, acc, 0, 0, 0);
        }
        // D: col=m (x), rows = 16*ys + 4g + q (y) -> scatter into V[y][x]
#pragma unroll
        for (int q = 0; q < 4; ++q)
            V[(16 * ys + 4 * g + q) * VROW + 16 * xs + m] = f2bf(acc[q]);
    }
    __syncthreads();

    // ---- step 2: hblur + fused epilogue (16 tiles: 4 x-tiles x 4 y-tiles) ----
#pragma unroll
    for (int k2 = 0; k2 < 2; ++k2) {
        const int t = wv + 8 * k2;
        const int xs = t & 3, ys = t >> 2;
        f32x4 acc = {0.f, 0.f, 0.f, 0.f};
#pragma unroll
        for (int rs = 0; rs < 3; ++rs) {
            const bf16x8 b = *(const bf16x8*)&V[(16 * ys + m) * VROW + 16 * xs + rs * 32 + 8 * g];
            acc = __builtin_amdgcn_mfma_f32_16x16x32_bf16(a1[rs], b, acc, 0, 0, 0);
        }
        // D: col=m (y), rows = 4g + q (x): 4 consecutive x at fixed y
        const size_t di = base + (size_t)(y0 + 16 * ys + m) * IMG + (x0 + 16 * xs + 4 * g);
        const f32x4 iv = *(const f32x4*)&img[di];
        if (STOREM == 1) {
            const unsigned d0 = (unsigned)f2bf(iv[0] - acc[0]) | ((unsigned)f2bf(iv[1] - acc[1]) << 16);
            const unsigned d1 = (unsigned)f2bf(iv[2] - acc[2]) | ((unsigned)f2bf(iv[3] - acc[3]) << 16);
            *(uint2*)&((unsigned short*)dstv)[di] = make_uint2(d0, d1);
        } else {
            const uint2 rv2 = *(const uint2*)&res[di];
            f32x4 o;
#pragma unroll
            for (int q = 0; q < 4; ++q) {
                const unsigned rw = (q < 2) ? rv2.x : rv2.y;
                const float rvq = bf2f((unsigned short)(rw >> ((q & 1) * 16)));
                float sharp = fmaf(0.5f, rvq, iv[q]);
                sharp = fminf(fmaxf(sharp, 0.f), 1.f);
                o[q] = fmaf(acc[q], sharp - iv[q], iv[q]);  // img + sm*(sharp-img)
            }
            *(f32x4*)&((float*)dstv)[di] = o;
        }
    }
}

extern "C" void kernel_launch(void* const* d_in, const int* in_sizes, int n_in,
                              void* d_out, int out_size, void* d_ws, size_t ws_size,
                              hipStream_t stream) {
    (void)in_sizes; (void)n_in; (void)out_size; (void)ws_size;
    const float* img = (const float*)d_in[0];
    const float* k1d = (const float*)d_in[1];
    float* out = (float*)d_out;
    unsigned short* rs = (unsigned short*)d_ws;  // 48*512*512*2 = 25165824 B

    const dim3 grid(IMG / TILE, IMG / TILE, NIMG);  // (8, 8, 48) = 3072 blocks

    fused_kern<0, 0, 1><<<grid, 512, 0, stream>>>(img, img, nullptr, rs, k1d);  // rs = residual
    fused_kern<1, 1, 2><<<grid, 512, 0, stream>>>(rs, img, rs, out, k1d);       // final
}